// Round 1
// baseline (1204.750 us; speedup 1.0000x reference)
//
#include <hip/hip_runtime.h>
#include <climits>

// ---------------- wave (64-lane) reductions ----------------
__device__ __forceinline__ float waveMax(float v) {
  #pragma unroll
  for (int o = 32; o > 0; o >>= 1) v = fmaxf(v, __shfl_xor(v, o));
  return v;
}
__device__ __forceinline__ float waveSum(float v) {
  #pragma unroll
  for (int o = 32; o > 0; o >>= 1) v += __shfl_xor(v, o);
  return v;
}

// ---------------- init: zero deg, seed min/max ----------------
__global__ void k_init(float* __restrict__ deg, int n, int* __restrict__ mm) {
  int i = blockIdx.x * blockDim.x + threadIdx.x;
  if (i < n) deg[i] = 0.f;
  if (i == 0) { mm[0] = INT_MAX; mm[1] = INT_MIN; }
}

// ---------------- min/max over edge_count ----------------
__global__ void k_minmax(const int* __restrict__ ec, int n, int* __restrict__ mm) {
  int i = blockIdx.x * blockDim.x + threadIdx.x;
  int stride = gridDim.x * blockDim.x;
  int vmin = INT_MAX, vmax = INT_MIN;
  for (; i < n; i += stride) {
    int v = ec[i];
    vmin = min(vmin, v);
    vmax = max(vmax, v);
  }
  #pragma unroll
  for (int o = 32; o > 0; o >>= 1) {
    vmin = min(vmin, __shfl_xor(vmin, o));
    vmax = max(vmax, __shfl_xor(vmax, o));
  }
  if ((threadIdx.x & 63) == 0) {
    atomicMin(&mm[0], vmin);
    atomicMax(&mm[1], vmax);
  }
}

// ---------------- degree accumulation: deg[col] += ew ----------------
__global__ void k_deg(const int* __restrict__ ecol, const int* __restrict__ ec,
                      const int* __restrict__ mm, float* __restrict__ deg, int nE) {
  int i = blockIdx.x * blockDim.x + threadIdx.x;
  if (i >= nE) return;
  float mn = (float)mm[0];
  float rcp = 1.0f / (float)(mm[1] - mm[0]);
  float ew = ((float)ec[i] - mn) * rcp;
  atomicAdd(&deg[ecol[i]], ew);
}

// ---------------- dinv = rsqrt(deg + 1) (self loop weight 1) ----------------
__global__ void k_dinv(const float* __restrict__ deg, float* __restrict__ dinv, int n) {
  int i = blockIdx.x * blockDim.x + threadIdx.x;
  if (i < n) dinv[i] = rsqrtf(deg[i] + 1.0f);
}

// ---------------- GEMM1: [n,256] x [256,64], one wave per row ----------------
__global__ __launch_bounds__(512) void k_gemm1(const float* __restrict__ x,
                                               const float* __restrict__ W,
                                               float* __restrict__ out, int n) {
  __shared__ float ws[256 * 64];
  for (int i = threadIdx.x; i < 256 * 64; i += 512) ws[i] = W[i];
  __syncthreads();
  int wv = threadIdx.x >> 6, lane = threadIdx.x & 63;
  int row = blockIdx.x * 8 + wv;
  if (row >= n) return;
  const float4* xr = (const float4*)(x + (size_t)row * 256);
  float acc = 0.f;
  #pragma unroll 8
  for (int k4 = 0; k4 < 64; ++k4) {
    float4 xv = xr[k4];
    int kb = k4 * 4;
    acc = fmaf(xv.x, ws[(kb + 0) * 64 + lane], acc);
    acc = fmaf(xv.y, ws[(kb + 1) * 64 + lane], acc);
    acc = fmaf(xv.z, ws[(kb + 2) * 64 + lane], acc);
    acc = fmaf(xv.w, ws[(kb + 3) * 64 + lane], acc);
  }
  out[(size_t)row * 64 + lane] = acc;
}

// ---------------- GEMM2: [n,64] x [64,64], one wave per row ----------------
__global__ __launch_bounds__(512) void k_gemm2(const float* __restrict__ h,
                                               const float* __restrict__ W,
                                               float* __restrict__ out, int n) {
  __shared__ float ws[64 * 64];
  for (int i = threadIdx.x; i < 64 * 64; i += 512) ws[i] = W[i];
  __syncthreads();
  int wv = threadIdx.x >> 6, lane = threadIdx.x & 63;
  int row = blockIdx.x * 8 + wv;
  if (row >= n) return;
  const float4* hr = (const float4*)(h + (size_t)row * 64);
  float acc = 0.f;
  #pragma unroll
  for (int k4 = 0; k4 < 16; ++k4) {
    float4 hv = hr[k4];
    int kb = k4 * 4;
    acc = fmaf(hv.x, ws[(kb + 0) * 64 + lane], acc);
    acc = fmaf(hv.y, ws[(kb + 1) * 64 + lane], acc);
    acc = fmaf(hv.z, ws[(kb + 2) * 64 + lane], acc);
    acc = fmaf(hv.w, ws[(kb + 3) * 64 + lane], acc);
  }
  out[(size_t)row * 64 + lane] = acc;
}

// ---------------- self-loop init: out = dinv^2 * xw ----------------
__global__ void k_self(const float* __restrict__ dinv, const float* __restrict__ xw,
                       float* __restrict__ out, int n64) {
  int i = blockIdx.x * blockDim.x + threadIdx.x;
  if (i >= n64) return;
  float di = dinv[i >> 6];
  out[i] = di * di * xw[i];
}

// ---------------- edge scatter: out[col] += norm * xw[row], one wave/edge ----
__global__ void k_scatter(const int* __restrict__ erow, const int* __restrict__ ecol,
                          const int* __restrict__ ec, const int* __restrict__ mm,
                          const float* __restrict__ dinv, const float* __restrict__ xw,
                          float* __restrict__ out, int nE) {
  int e = blockIdx.x * (blockDim.x >> 6) + (threadIdx.x >> 6);
  if (e >= nE) return;
  int lane = threadIdx.x & 63;
  int r = erow[e], c = ecol[e];
  float mn = (float)mm[0];
  float rcp = 1.0f / (float)(mm[1] - mm[0]);
  float ew = ((float)ec[e] - mn) * rcp;
  float nrm = dinv[r] * ew * dinv[c];
  atomicAdd(&out[(size_t)c * 64 + lane], nrm * xw[(size_t)r * 64 + lane]);
}

// ---------------- bias + relu (layer 1 post) ----------------
__global__ void k_bias_relu(float* __restrict__ h, const float* __restrict__ b, int n64) {
  int i = blockIdx.x * blockDim.x + threadIdx.x;
  if (i >= n64) return;
  h[i] = fmaxf(h[i] + b[i & 63], 0.f);
}

// ---------------- final: bias, write embeddings, log_softmax ----------------
__global__ void k_final(float* __restrict__ out, const float* __restrict__ b, int n) {
  int wv = threadIdx.x >> 6, lane = threadIdx.x & 63;
  int row = blockIdx.x * (blockDim.x >> 6) + wv;
  if (row >= n) return;
  size_t idx = (size_t)row * 64 + lane;
  float v = out[idx] + b[lane];
  out[idx] = v;
  float m = waveMax(v);
  float s = waveSum(expf(v - m));
  out[(size_t)n * 64 + idx] = v - m - logf(s);
}

extern "C" void kernel_launch(void* const* d_in, const int* in_sizes, int n_in,
                              void* d_out, int out_size, void* d_ws, size_t ws_size,
                              hipStream_t stream) {
  const float* x  = (const float*)d_in[0];
  const int*   ei = (const int*)d_in[1];
  const int*   ec = (const int*)d_in[2];
  const float* W1 = (const float*)d_in[3];
  const float* b1 = (const float*)d_in[4];
  const float* W2 = (const float*)d_in[5];
  const float* b2 = (const float*)d_in[6];

  int nN = in_sizes[0] / 256;   // 100000
  int nE = in_sizes[2];         // 1600000
  const int* erow = ei;
  const int* ecol = ei + nE;

  int* mm = (int*)d_ws;
  float* wsf = (float*)d_ws;
  int nNp = (nN + 255) & ~255;               // padded node count
  float* deg  = wsf + 64;
  float* dinv = deg + nNp;
  float* xw   = dinv + nNp;                  // [nN,64] linear output
  float* h1   = xw + (size_t)nNp * 64;       // [nN,64] aggregated / hidden
  float* outp = (float*)d_out;

  int n64 = nN * 64;

  k_init<<<(nN + 255) / 256, 256, 0, stream>>>(deg, nN, mm);
  k_minmax<<<1024, 256, 0, stream>>>(ec, nE, mm);
  k_deg<<<(nE + 255) / 256, 256, 0, stream>>>(ecol, ec, mm, deg, nE);
  k_dinv<<<(nN + 255) / 256, 256, 0, stream>>>(deg, dinv, nN);

  // ---- layer 1 ----
  k_gemm1<<<(nN + 7) / 8, 512, 0, stream>>>(x, W1, xw, nN);
  k_self<<<(n64 + 255) / 256, 256, 0, stream>>>(dinv, xw, h1, n64);
  k_scatter<<<(nE + 3) / 4, 256, 0, stream>>>(erow, ecol, ec, mm, dinv, xw, h1, nE);
  k_bias_relu<<<(n64 + 255) / 256, 256, 0, stream>>>(h1, b1, n64);

  // ---- layer 2 ----
  k_gemm2<<<(nN + 7) / 8, 512, 0, stream>>>(h1, W2, xw, nN);
  k_self<<<(n64 + 255) / 256, 256, 0, stream>>>(dinv, xw, outp, n64);
  k_scatter<<<(nE + 3) / 4, 256, 0, stream>>>(erow, ecol, ec, mm, dinv, xw, outp, nE);

  // ---- bias + log_softmax ----
  k_final<<<(nN + 3) / 4, 256, 0, stream>>>(outp, b2, nN);
}

// Round 2
// 971.969 us; speedup vs baseline: 1.2395x; 1.2395x over previous
//
#include <hip/hip_runtime.h>
#include <climits>

// ---------------- wave (64-lane) reductions ----------------
__device__ __forceinline__ float waveMax(float v) {
  #pragma unroll
  for (int o = 32; o > 0; o >>= 1) v = fmaxf(v, __shfl_xor(v, o));
  return v;
}
__device__ __forceinline__ float waveSum(float v) {
  #pragma unroll
  for (int o = 32; o > 0; o >>= 1) v += __shfl_xor(v, o);
  return v;
}

// ---------------- zero counters, seed min/max ----------------
__global__ void k_zero(int* __restrict__ cnt, float* __restrict__ deg,
                       int* __restrict__ gctr, int* __restrict__ mm, int n) {
  int i = blockIdx.x * blockDim.x + threadIdx.x;
  if (i < n) { cnt[i] = 0; deg[i] = 0.f; }
  if (i == 0) { *gctr = 0; mm[0] = INT_MAX; mm[1] = INT_MIN; }
}

// ---------------- min/max over edge_count ----------------
__global__ void k_minmax(const int* __restrict__ ec, int n, int* __restrict__ mm) {
  int i = blockIdx.x * blockDim.x + threadIdx.x;
  int stride = gridDim.x * blockDim.x;
  int vmin = INT_MAX, vmax = INT_MIN;
  for (; i < n; i += stride) {
    int v = ec[i];
    vmin = min(vmin, v);
    vmax = max(vmax, v);
  }
  #pragma unroll
  for (int o = 32; o > 0; o >>= 1) {
    vmin = min(vmin, __shfl_xor(vmin, o));
    vmax = max(vmax, __shfl_xor(vmax, o));
  }
  if ((threadIdx.x & 63) == 0) {
    atomicMin(&mm[0], vmin);
    atomicMax(&mm[1], vmax);
  }
}

// ---------------- histogram: cnt[col]++, deg[col] += ew ----------------
__global__ void k_hist(const int* __restrict__ ecol, const int* __restrict__ ec,
                       const int* __restrict__ mm, int* __restrict__ cnt,
                       float* __restrict__ deg, int nE) {
  int i = blockIdx.x * blockDim.x + threadIdx.x;
  if (i >= nE) return;
  float mn = (float)mm[0];
  float rcp = 1.0f / (float)(mm[1] - mm[0]);
  float ew = ((float)ec[i] - mn) * rcp;
  int c = ecol[i];
  atomicAdd(&cnt[c], 1);
  atomicAdd(&deg[c], ew);
}

// ---------------- segment base offsets via wave scan + one atomic/wave ------
__global__ void k_base(const int* __restrict__ cnt, int* __restrict__ rowptr,
                       int* __restrict__ cursor, int* __restrict__ gctr, int n) {
  int i = blockIdx.x * blockDim.x + threadIdx.x;
  int lane = threadIdx.x & 63;
  int v = (i < n) ? cnt[i] : 0;
  int s = v;
  #pragma unroll
  for (int o = 1; o < 64; o <<= 1) {
    int t = __shfl_up(s, o);
    if (lane >= o) s += t;
  }
  int wtot = __shfl(s, 63);
  int base = 0;
  if (lane == 63) base = atomicAdd(gctr, wtot);
  base = __shfl(base, 63);
  int excl = base + s - v;
  if (i < n) { rowptr[i] = excl; cursor[i] = excl; }
}

// ---------------- dinv = rsqrt(deg + 1) ----------------
__global__ void k_dinv(const float* __restrict__ deg, float* __restrict__ dinv, int n) {
  int i = blockIdx.x * blockDim.x + threadIdx.x;
  if (i < n) dinv[i] = rsqrtf(deg[i] + 1.0f);
}

// ---------------- fill CSR: srcw[p] = {row, ew} ----------------
__global__ void k_fill(const int* __restrict__ erow, const int* __restrict__ ecol,
                       const int* __restrict__ ec, const int* __restrict__ mm,
                       int* __restrict__ cursor, int2* __restrict__ srcw, int nE) {
  int e = blockIdx.x * blockDim.x + threadIdx.x;
  if (e >= nE) return;
  float mn = (float)mm[0];
  float rcp = 1.0f / (float)(mm[1] - mm[0]);
  float ew = ((float)ec[e] - mn) * rcp;
  int c = ecol[e];
  int p = atomicAdd(&cursor[c], 1);
  srcw[p] = make_int2(erow[e], __float_as_int(ew));
}

// ---------------- GEMM1: [n,256] x [256,64], 4 rows per wave, swizzled LDS --
__global__ __launch_bounds__(512) void k_gemm1(const float* __restrict__ x,
                                               const float* __restrict__ W,
                                               float* __restrict__ out, int n) {
  // ws4[j*64 + (k4 ^ (j&31))] holds W[k4*4 .. k4*4+3][j]  (64 KB)
  __shared__ float4 ws4[64 * 64];
  for (int idx = threadIdx.x; idx < 256 * 64; idx += 512) {
    int k = idx >> 6, j = idx & 63;
    int k4 = k >> 2, kr = k & 3;
    ((float*)&ws4[j * 64 + (k4 ^ (j & 31))])[kr] = W[idx];
  }
  __syncthreads();
  int wv = threadIdx.x >> 6, lane = threadIdx.x & 63;
  int row0 = (blockIdx.x * 8 + wv) * 4;
  if (row0 >= n) return;
  const float4* x0 = (const float4*)(x + (size_t)row0 * 256);
  float a0 = 0.f, a1 = 0.f, a2 = 0.f, a3 = 0.f;
  if (row0 + 4 <= n) {
    #pragma unroll 4
    for (int k4 = 0; k4 < 64; ++k4) {
      float4 w4 = ws4[lane * 64 + (k4 ^ (lane & 31))];
      float4 v0 = x0[k4], v1 = x0[64 + k4], v2 = x0[128 + k4], v3 = x0[192 + k4];
      a0 = fmaf(v0.x, w4.x, a0); a0 = fmaf(v0.y, w4.y, a0); a0 = fmaf(v0.z, w4.z, a0); a0 = fmaf(v0.w, w4.w, a0);
      a1 = fmaf(v1.x, w4.x, a1); a1 = fmaf(v1.y, w4.y, a1); a1 = fmaf(v1.z, w4.z, a1); a1 = fmaf(v1.w, w4.w, a1);
      a2 = fmaf(v2.x, w4.x, a2); a2 = fmaf(v2.y, w4.y, a2); a2 = fmaf(v2.z, w4.z, a2); a2 = fmaf(v2.w, w4.w, a2);
      a3 = fmaf(v3.x, w4.x, a3); a3 = fmaf(v3.y, w4.y, a3); a3 = fmaf(v3.z, w4.z, a3); a3 = fmaf(v3.w, w4.w, a3);
    }
    out[(size_t)row0 * 64 + lane] = a0;
    out[(size_t)(row0 + 1) * 64 + lane] = a1;
    out[(size_t)(row0 + 2) * 64 + lane] = a2;
    out[(size_t)(row0 + 3) * 64 + lane] = a3;
  } else {
    for (int r = row0; r < n; ++r) {
      const float4* xr = (const float4*)(x + (size_t)r * 256);
      float acc = 0.f;
      for (int k4 = 0; k4 < 64; ++k4) {
        float4 w4 = ws4[lane * 64 + (k4 ^ (lane & 31))];
        float4 xv = xr[k4];
        acc = fmaf(xv.x, w4.x, acc); acc = fmaf(xv.y, w4.y, acc);
        acc = fmaf(xv.z, w4.z, acc); acc = fmaf(xv.w, w4.w, acc);
      }
      out[(size_t)r * 64 + lane] = acc;
    }
  }
}

// ---------------- GEMM2: [n,64] x [64,64], one wave per row ----------------
__global__ __launch_bounds__(512) void k_gemm2(const float* __restrict__ h,
                                               const float* __restrict__ W,
                                               float* __restrict__ out, int n) {
  __shared__ float ws[64 * 64];
  for (int i = threadIdx.x; i < 64 * 64; i += 512) ws[i] = W[i];
  __syncthreads();
  int wv = threadIdx.x >> 6, lane = threadIdx.x & 63;
  int row = blockIdx.x * 8 + wv;
  if (row >= n) return;
  const float4* hr = (const float4*)(h + (size_t)row * 64);
  float acc = 0.f;
  #pragma unroll
  for (int k4 = 0; k4 < 16; ++k4) {
    float4 hv = hr[k4];
    int kb = k4 * 4;
    acc = fmaf(hv.x, ws[(kb + 0) * 64 + lane], acc);
    acc = fmaf(hv.y, ws[(kb + 1) * 64 + lane], acc);
    acc = fmaf(hv.z, ws[(kb + 2) * 64 + lane], acc);
    acc = fmaf(hv.w, ws[(kb + 3) * 64 + lane], acc);
  }
  out[(size_t)row * 64 + lane] = acc;
}

// ---------------- aggregate layer 1: gather-add + bias + relu --------------
__global__ void k_agg1(const int* __restrict__ rowptr, const int* __restrict__ cnt,
                       const int2* __restrict__ srcw, const float* __restrict__ dinv,
                       const float* __restrict__ xw, const float* __restrict__ b,
                       float* __restrict__ h1, int nN) {
  int node = blockIdx.x * 4 + (threadIdx.x >> 6);
  if (node >= nN) return;
  int lane = threadIdx.x & 63;
  float dc = dinv[node];
  float acc = dc * dc * xw[(size_t)node * 64 + lane];
  int s = rowptr[node], e = s + cnt[node];
  for (int p = s; p < e; ++p) {
    int2 rw = srcw[p];
    float nrm = dinv[rw.x] * __int_as_float(rw.y) * dc;
    acc = fmaf(nrm, xw[(size_t)rw.x * 64 + lane], acc);
  }
  h1[(size_t)node * 64 + lane] = fmaxf(acc + b[lane], 0.f);
}

// ---------------- aggregate layer 2: gather-add + bias + log_softmax -------
__global__ void k_agg2(const int* __restrict__ rowptr, const int* __restrict__ cnt,
                       const int2* __restrict__ srcw, const float* __restrict__ dinv,
                       const float* __restrict__ xw, const float* __restrict__ b,
                       float* __restrict__ outp, int nN) {
  int node = blockIdx.x * 4 + (threadIdx.x >> 6);
  if (node >= nN) return;
  int lane = threadIdx.x & 63;
  float dc = dinv[node];
  float acc = dc * dc * xw[(size_t)node * 64 + lane];
  int s = rowptr[node], e = s + cnt[node];
  for (int p = s; p < e; ++p) {
    int2 rw = srcw[p];
    float nrm = dinv[rw.x] * __int_as_float(rw.y) * dc;
    acc = fmaf(nrm, xw[(size_t)rw.x * 64 + lane], acc);
  }
  float v = acc + b[lane];
  size_t idx = (size_t)node * 64 + lane;
  outp[idx] = v;
  float m = waveMax(v);
  float sum = waveSum(expf(v - m));
  outp[(size_t)nN * 64 + idx] = v - m - logf(sum);
}

extern "C" void kernel_launch(void* const* d_in, const int* in_sizes, int n_in,
                              void* d_out, int out_size, void* d_ws, size_t ws_size,
                              hipStream_t stream) {
  const float* x  = (const float*)d_in[0];
  const int*   ei = (const int*)d_in[1];
  const int*   ec = (const int*)d_in[2];
  const float* W1 = (const float*)d_in[3];
  const float* b1 = (const float*)d_in[4];
  const float* W2 = (const float*)d_in[5];
  const float* b2 = (const float*)d_in[6];

  int nN = in_sizes[0] / 256;   // 100000
  int nE = in_sizes[2];         // 1600000
  const int* erow = ei;
  const int* ecol = ei + nE;
  int n64 = nN * 64;

  // ---- workspace layout (4B units) ----
  int*   wsi    = (int*)d_ws;
  int*   mm     = wsi;            // 2
  int*   gctr   = wsi + 2;        // 1
  int*   cnt    = wsi + 16;
  int*   rowptr = cnt + nN;
  int*   cursor = rowptr + nN;
  float* deg    = (float*)(cursor + nN);
  float* dinv   = deg + nN;
  int2*  srcw   = (int2*)(dinv + nN);        // offset 16+5*nN (even) -> 8B aligned
  float* xw     = (float*)(srcw + nE);       // [nN,64]
  float* h1     = xw + (size_t)n64;          // [nN,64]
  float* outp   = (float*)d_out;

  // ---- CSR build + normalization ----
  k_zero<<<(nN + 255) / 256, 256, 0, stream>>>(cnt, deg, gctr, mm, nN);
  k_minmax<<<1024, 256, 0, stream>>>(ec, nE, mm);
  k_hist<<<(nE + 255) / 256, 256, 0, stream>>>(ecol, ec, mm, cnt, deg, nE);
  k_base<<<(nN + 255) / 256, 256, 0, stream>>>(cnt, rowptr, cursor, gctr, nN);
  k_dinv<<<(nN + 255) / 256, 256, 0, stream>>>(deg, dinv, nN);
  k_fill<<<(nE + 255) / 256, 256, 0, stream>>>(erow, ecol, ec, mm, cursor, srcw, nE);

  // ---- layer 1 ----
  k_gemm1<<<(nN + 31) / 32, 512, 0, stream>>>(x, W1, xw, nN);
  k_agg1<<<(nN + 3) / 4, 256, 0, stream>>>(rowptr, cnt, srcw, dinv, xw, b1, h1, nN);

  // ---- layer 2 ----
  k_gemm2<<<(nN + 7) / 8, 512, 0, stream>>>(h1, W2, xw, nN);
  k_agg2<<<(nN + 3) / 4, 256, 0, stream>>>(rowptr, cnt, srcw, dinv, xw, b2, outp, nN);
}